// Round 5
// baseline (109.691 us; speedup 1.0000x reference)
//
#include <hip/hip_runtime.h>
#include <math.h>

// MinibatchDiscrimination: B=512, IN=512, OUT=100, K=5
//   M = x @ T.view(512,500);  out[j,o] = sum_i exp(-sum_k|M[i,o,k]-M[j,o,k]|) - 1
//
// 2 dispatches:
//  prep : xT[c][i] = x[i][c]  (coalesced GEMM reads), Ts = T * log2(e)
//         (|s*a - s*b| = s*|a-b| for s>0, so exp(-n) == exp2(-n_scaled))
//  fused: grid (100 o, 2 j-halves) x 512 thr.
//         GEMM phase: thread = 4 i-rows x 1/4 c-range; T via wave-uniform
//         s_loads; partials ds_add_f32 into LDS Ms[512][8]. No staging tiles,
//         no inner barriers (R1-R4 tiled gemm was latency-bound at <8% VALU).
//         Pairwise phase: 4 j/thread register-blocked (amortizes the 20B/i
//         LDS read 4x; R4's 1 j/thread was LDS-instruction-bound ~12us).

#define NB    512
#define NIN   512
#define NOUT  100
#define KDIM  5
#define NCOL  (NOUT*KDIM)   // 500
#define LOG2E 1.44269504088896340736f

// ---------------- prep: transpose x + scale T
__global__ __launch_bounds__(256) void prep_kernel(const float* __restrict__ x,
                                                   const float* __restrict__ T,
                                                   float* __restrict__ xT,
                                                   float* __restrict__ Ts) {
    const int bx = blockIdx.x;
    if (bx < 256) {
        // 32x32 transpose tile; 256 thr = 32x8
        __shared__ float tile[32][33];
        const int tr = bx >> 4, tc = bx & 15;
        const int tx = threadIdx.x & 31, ty = threadIdx.x >> 5;
        #pragma unroll
        for (int l = 0; l < 4; ++l)
            tile[ty + 8 * l][tx] = x[(tr * 32 + ty + 8 * l) * NIN + tc * 32 + tx];
        __syncthreads();
        #pragma unroll
        for (int l = 0; l < 4; ++l)
            xT[(tc * 32 + ty + 8 * l) * NB + tr * 32 + tx] = tile[tx][ty + 8 * l];
    } else {
        // scale T: 512*500 floats = exactly 64000 float4 over 250 blocks
        const int idx = (bx - 256) * 256 + threadIdx.x;
        float4 v = reinterpret_cast<const float4*>(T)[idx];
        v.x *= LOG2E; v.y *= LOG2E; v.z *= LOG2E; v.w *= LOG2E;
        reinterpret_cast<float4*>(Ts)[idx] = v;
    }
}

// ---------------- fused GEMM + pairwise
__global__ __launch_bounds__(512) void fused_kernel(const float* __restrict__ xT,
                                                    const float* __restrict__ Ts,
                                                    float* __restrict__ out) {
    __shared__ float Ms[NB * 8];        // 16 KB: Ms[i*8+k], scaled M_o
    __shared__ float Pw[8][64][4];      // 8 KB : i-split partials

    const int o  = blockIdx.x;          // 0..99
    const int jc = blockIdx.y;          // 0..1
    const int t  = threadIdx.x;         // 0..511

    // zero Ms (atomic accumulation target)
    #pragma unroll
    for (int l = 0; l < 8; ++l) Ms[t + 512 * l] = 0.0f;
    __syncthreads();

    // ---- GEMM phase: M'[i][k] = sum_c xT[c][i] * Ts[c][o*5+k]
    {
        const int ih = t & 127;          // 128 groups of 4 rows
        const int cs = t >> 7;           // 4 c-splits of 128
        const int i0 = ih * 4;
        const float* Tcol = Ts + o * KDIM;
        float acc[4][5];
        #pragma unroll
        for (int r = 0; r < 4; ++r)
            #pragma unroll
            for (int k = 0; k < 5; ++k) acc[r][k] = 0.0f;

        const int cbeg = cs * 128;
        #pragma unroll 4
        for (int c = cbeg; c < cbeg + 128; ++c) {
            const float4 xv = *reinterpret_cast<const float4*>(&xT[c * NB + i0]);
            const float* tk = &Tcol[c * NCOL];   // wave-uniform -> s_load
            #pragma unroll
            for (int k = 0; k < 5; ++k) {
                const float tv = tk[k];
                acc[0][k] = fmaf(xv.x, tv, acc[0][k]);
                acc[1][k] = fmaf(xv.y, tv, acc[1][k]);
                acc[2][k] = fmaf(xv.z, tv, acc[2][k]);
                acc[3][k] = fmaf(xv.w, tv, acc[3][k]);
            }
        }
        #pragma unroll
        for (int r = 0; r < 4; ++r)
            #pragma unroll
            for (int k = 0; k < 5; ++k)
                atomicAdd(&Ms[(i0 + r) * 8 + k], acc[r][k]);   // ds_add_f32
    }
    __syncthreads();

    // ---- pairwise phase: thread = (jg: 4 j's, is: 64 i's)
    const int jg = t & 63;
    const int is = t >> 6;
    const int jbase = jc * 256 + jg * 4;

    float jv[4][5];
    #pragma unroll
    for (int jj = 0; jj < 4; ++jj) {
        const float* m = &Ms[(jbase + jj) * 8];
        #pragma unroll
        for (int k = 0; k < 5; ++k) jv[jj][k] = m[k];
    }

    float acc[4] = {0.f, 0.f, 0.f, 0.f};
    const int ibeg = is * 64;
    #pragma unroll 2
    for (int i = ibeg; i < ibeg + 64; ++i) {
        const float* m = &Ms[i * 8];
        const float m0 = m[0], m1 = m[1], m2 = m[2], m3 = m[3], m4 = m[4];
        #pragma unroll
        for (int jj = 0; jj < 4; ++jj) {
            const float n = fabsf(m0 - jv[jj][0]) + fabsf(m1 - jv[jj][1])
                          + fabsf(m2 - jv[jj][2]) + fabsf(m3 - jv[jj][3])
                          + fabsf(m4 - jv[jj][4]);
            acc[jj] += exp2f(-n);       // M pre-scaled by log2e -> e^(-norm)
        }
    }

    *reinterpret_cast<float4*>(&Pw[is][jg][0]) = make_float4(acc[0], acc[1], acc[2], acc[3]);
    __syncthreads();

    if (t < 64) {
        #pragma unroll
        for (int jj = 0; jj < 4; ++jj) {
            float tot = -1.0f;          // remove exp(0) self-term
            #pragma unroll
            for (int s = 0; s < 8; ++s) tot += Pw[s][t][jj];
            out[(jc * 256 + t * 4 + jj) * NOUT + o] = tot;
        }
    }
}

extern "C" void kernel_launch(void* const* d_in, const int* in_sizes, int n_in,
                              void* d_out, int out_size, void* d_ws, size_t ws_size,
                              hipStream_t stream) {
    const float* x = (const float*)d_in[0];   // [512,512]
    const float* T = (const float*)d_in[1];   // [512,500]
    float* xT = (float*)d_ws;                 // [512,512]  1 MB
    float* Ts = xT + NB * NIN;                // [512,500]  1 MB
    float* out = (float*)d_out;               // [512,100]

    prep_kernel<<<506, 256, 0, stream>>>(x, T, xT, Ts);
    fused_kernel<<<dim3(NOUT, 2), 512, 0, stream>>>(xT, Ts, out);
}